// Round 23
// baseline (215.702 us; speedup 1.0000x reference)
//
#include <hip/hip_runtime.h>
#include <hip/hip_bf16.h>

#define BSH 9
#define BSZ 512    // nodes per bucket
#define CAP 17408  // edge capacity per bucket (mean 16384 + 8 sigma)
#define CHK 4096   // edges per scatter block (16 per thread)

typedef __attribute__((ext_vector_type(8))) short bf16x8;
typedef __attribute__((ext_vector_type(4))) float f32x4;

__device__ __forceinline__ unsigned short f2bf(float f) {  // RN-even fp32->bf16
    unsigned u = __float_as_uint(f);
    u += 0x7fffu + ((u >> 16) & 1u);
    return (unsigned short)(u >> 16);
}
__device__ __forceinline__ float b2f(unsigned short v) {
    return __uint_as_float((unsigned)v << 16);
}
__device__ __forceinline__ float b2f_lo(unsigned int v) {
    return __uint_as_float(v << 16);
}
__device__ __forceinline__ float b2f_hi(unsigned int v) {
    return __uint_as_float(v & 0xffff0000u);
}

// init bucket cursors to fixed bases
__global__ void init_k(int* __restrict__ curD, int* __restrict__ curS, int nbk) {
    int i = threadIdx.x;
    if (i < nbk) { curD[i] = i * CAP; curS[i] = i * CAP; }
}

// ---------------- fused: MFMA GEMM1 (coop W-frag staging) + bucket-sort scatter (R16) -------
// blocks [0, nGm): gemm (64 rows, 4 waves x one 16-row tile).
// blocks [nGm, nGm+NBLK): scatter.
// pairs packed: (src << 9) | (dst & 511).  sbuf: low 9 bits of src (ushort).

#define GROWS 64
#define GKC 256
#define GSTR 264   // bf16 row stride: 132 dwords == 4 mod 32 -> 2-way banks (free)

__global__ __launch_bounds__(256) void fused_gs_k(
    const float* __restrict__ X, const float* __restrict__ W, const float* __restrict__ B,
    float* __restrict__ H, int n, int nGm,
    const int* __restrict__ src, const int* __restrict__ dst, int E,
    int* __restrict__ curD, int* __restrict__ curS,
    unsigned int* __restrict__ pairs, unsigned short* __restrict__ sbuf, int nbk) {
    __shared__ char smem[GROWS * GSTR * 2];   // 33.8 KB union (gemm tile | scatter stage)
    int t = threadIdx.x;

    if ((int)blockIdx.x < nGm) {
        // ---- GEMM path ----
        unsigned short* xt = (unsigned short*)smem;
        int lane = t & 63, wave = t >> 6;
        int rowBase = blockIdx.x * GROWS;
        int bn = lane & 15;

        // cooperative W -> bf16 frag staging (frag table [16 kt][4 kg][16 bn][8 j] in xt)
        {
            int kt0 = t >> 4, kg0 = (t >> 2) & 3, bn0 = (t & 3) * 4;
            unsigned short frag[4][8];
#pragma unroll
            for (int j = 0; j < 8; ++j) {
                float4 w = *(const float4*)&W[(size_t)(kt0 * 32 + kg0 * 8 + j) * 16 + bn0];
                frag[0][j] = f2bf(w.x); frag[1][j] = f2bf(w.y);
                frag[2][j] = f2bf(w.z); frag[3][j] = f2bf(w.w);
            }
#pragma unroll
            for (int b = 0; b < 4; ++b)
                *(uint4*)&xt[((kt0 * 4 + kg0) * 16 + bn0 + b) * 8] = *(const uint4*)frag[b];
        }
        __syncthreads();
        bf16x8 bw[16];
#pragma unroll
        for (int kt = 0; kt < 16; ++kt)
            bw[kt] = *(const bf16x8*)&xt[(kt * 64 + lane) * 8];
        float bias = B[bn];
        __syncthreads();   // bw reads done before X staging overwrites

        f32x4 acc = {0.f, 0.f, 0.f, 0.f};
        int srow = t >> 4, skq = t & 15;

        for (int ch = 0; ch < 2; ++ch) {
#pragma unroll
            for (int p = 0; p < 4; ++p) {
                int r = p * 16 + srow;
                int gr = rowBase + r;
                const float* xr = &X[(size_t)(gr < n ? gr : n - 1) * 512 + ch * GKC + skq * 4];
#pragma unroll
                for (int q = 0; q < 4; ++q) {
                    float4 v = *(const float4*)&xr[q * 64];
                    ushort4 u;
                    u.x = f2bf(v.x); u.y = f2bf(v.y); u.z = f2bf(v.z); u.w = f2bf(v.w);
                    *(ushort4*)&xt[r * GSTR + skq * 4 + q * 64] = u;
                }
            }
            __syncthreads();

            int rb = (wave * 16 + bn) * GSTR + (lane >> 4) * 8;
#pragma unroll
            for (int kt = 0; kt < 8; ++kt) {
                bf16x8 af = *(const bf16x8*)&xt[rb + kt * 32];
                acc = __builtin_amdgcn_mfma_f32_16x16x32_bf16(af, bw[ch * 8 + kt], acc, 0, 0, 0);
            }
            __syncthreads();
        }

        int r0 = rowBase + wave * 16 + (lane >> 4) * 4;
#pragma unroll
        for (int i = 0; i < 4; ++i) {
            int row = r0 + i;
            if (row < n) H[(size_t)row * 16 + bn] = acc[i] + bias;
        }
    } else {
        // ---- scatter path: register-batched LDS bucket sort -> coalesced burst writes ----
        unsigned int*   stageD = (unsigned int*)smem;             // 4096 * 4B
        unsigned short* stageS = (unsigned short*)(smem + 16384); // 4096 * 2B
        int* cntD  = (int*)(smem + 24576);
        int* cntS  = (int*)(smem + 25600);
        int* rsvD  = (int*)(smem + 26624);
        int* rsvS  = (int*)(smem + 27648);
        int* scanD = (int*)(smem + 28672);
        int* scanS = (int*)(smem + 29696);
        int* ps    = (int*)(smem + 30720);

        int bb = blockIdx.x - nGm;
        int lo = bb * CHK, hi = min(E, lo + CHK);
        bool full = (hi - lo) == CHK;

        cntD[t] = 0; cntS[t] = 0;
        __syncthreads();

        int sv[16], dv[16];
        if (full) {
#pragma unroll
            for (int j = 0; j < 16; j++) {
                int i = lo + t + j * 256;
                sv[j] = src[i]; dv[j] = dst[i];
            }
#pragma unroll
            for (int j = 0; j < 16; j++) {
                atomicAdd(&cntD[dv[j] >> BSH], 1);
                atomicAdd(&cntS[sv[j] >> BSH], 1);
            }
        } else {
            for (int i = lo + t; i < hi; i += 256) {
                atomicAdd(&cntD[dst[i] >> BSH], 1);
                atomicAdd(&cntS[src[i] >> BSH], 1);
            }
        }
        __syncthreads();
        int vD = cntD[t];
        ps[t] = vD; __syncthreads();
        for (int o = 1; o < 256; o <<= 1) {
            int u = (t >= o) ? ps[t - o] : 0; __syncthreads();
            ps[t] += u; __syncthreads();
        }
        scanD[t] = ps[t] - vD;
        if (t < nbk && vD) rsvD[t] = atomicAdd(&curD[t], vD);
        __syncthreads();
        int vS = cntS[t];
        ps[t] = vS; __syncthreads();
        for (int o = 1; o < 256; o <<= 1) {
            int u = (t >= o) ? ps[t - o] : 0; __syncthreads();
            ps[t] += u; __syncthreads();
        }
        scanS[t] = ps[t] - vS;
        if (t < nbk && vS) rsvS[t] = atomicAdd(&curS[t], vS);
        cntD[t] = 0; cntS[t] = 0;
        __syncthreads();
        if (full) {
#pragma unroll
            for (int j = 0; j < 16; j++) {
                int s = sv[j], d = dv[j];
                int bd = d >> BSH;
                int pd = scanD[bd] + atomicAdd(&cntD[bd], 1);
                stageD[pd] = ((unsigned int)s << BSH) | (unsigned int)(d & (BSZ - 1));
                int bs = s >> BSH;
                int pp = scanS[bs] + atomicAdd(&cntS[bs], 1);
                stageS[pp] = (unsigned short)(s & (BSZ - 1));
            }
        } else {
            for (int i = lo + t; i < hi; i += 256) {
                int s = src[i], d = dst[i];
                int bd = d >> BSH;
                int pd = scanD[bd] + atomicAdd(&cntD[bd], 1);
                stageD[pd] = ((unsigned int)s << BSH) | (unsigned int)(d & (BSZ - 1));
                int bs = s >> BSH;
                int pp = scanS[bs] + atomicAdd(&cntS[bs], 1);
                stageS[pp] = (unsigned short)(s & (BSZ - 1));
            }
        }
        __syncthreads();
        int wave = t >> 6, lane = t & 63;
        for (int b = wave; b < nbk; b += 4) {
            int st = scanD[b], len = cntD[b], g = rsvD[b];
            for (int j = lane; j < len; j += 64) pairs[g + j] = stageD[st + j];
        }
        for (int b = wave; b < nbk; b += 4) {
            int st = scanS[b], len = cntS[b], g = rsvS[b];
            for (int j = lane; j < len; j += 64) sbuf[g + j] = stageS[st + j];
        }
    }
}

// ---------------- dinv (src-degree) + scale h1 -> bf16 hw1 (hw1 = dinv * h1) ----------------

__global__ __launch_bounds__(256) void dinvScale_k(const unsigned short* __restrict__ sbuf,
                                                   const int* __restrict__ curS,
                                                   const float* __restrict__ h1,
                                                   float* __restrict__ dinv,
                                                   unsigned short* __restrict__ hw1, int n) {
    __shared__ int cnt[BSZ];
    __shared__ float dl[BSZ];
    int b = blockIdx.x, t = threadIdx.x;
    cnt[t] = 0; cnt[t + 256] = 0;
    __syncthreads();
    int lo = b * CAP, hi = curS[b];
    for (int i = lo + t; i < hi; i += 256) atomicAdd(&cnt[sbuf[i]], 1);
    __syncthreads();
    int n0 = b * BSZ + t, n1 = n0 + 256;
    float d0 = rsqrtf((float)(1 + cnt[t]));
    float d1 = rsqrtf((float)(1 + cnt[t + 256]));
    dl[t] = d0; dl[t + 256] = d1;
    if (n0 < n) dinv[n0] = d0;
    if (n1 < n) dinv[n1] = d1;
    __syncthreads();
    int rows = min(BSZ, n - b * BSZ);
    int lim4 = rows * 4;
    size_t base = (size_t)b * BSZ * 16;
#pragma unroll
    for (int j = 0; j < 8; j++) {
        int i4 = j * 256 + t;
        if (i4 < lim4) {
            float4 v = *(const float4*)&h1[base + (size_t)i4 * 4];
            float d = dl[i4 >> 2];
            ushort4 u;
            u.x = f2bf(v.x * d); u.y = f2bf(v.y * d);
            u.z = f2bf(v.z * d); u.w = f2bf(v.w * d);
            *(ushort4*)&hw1[base + (size_t)i4 * 4] = u;
        }
    }
}

// ---------------- bucket-centric aggregation (INT fixed-point LDS atomics) ------------------
// 2 lanes/edge x 16B gathers, 4-deep batch ILP: 512 edge slots per trip.

#define FPS 65536.f
#define FPI (1.f / 65536.f)

template <int LAYER>
__global__ __launch_bounds__(1024) void aggB_k(
    const unsigned int* __restrict__ pairs, const int* __restrict__ curD,
    const unsigned short* __restrict__ HW, const float* __restrict__ dinv,
    float* __restrict__ rowsum, const float* __restrict__ W2,
    const float* __restrict__ B2, unsigned short* __restrict__ outA,
    float* __restrict__ outF, int n, int nc) {
    __shared__ int iacc[BSZ * 16];        // 32 KB
    __shared__ unsigned int rsl[BSZ];     // 2 KB (layer 1)
    int b = blockIdx.x, t = threadIdx.x;
    for (int i = t; i < BSZ * 16; i += 1024) iacc[i] = 0;
    if (LAYER == 1 && t < BSZ) rsl[t] = 0u;
    __syncthreads();

    int lo = b * CAP, hi = curD[b];
    int h = t & 1;                 // feature half: 8 floats (16B of bf16)
    int i = lo + (t >> 1);         // 512 edge slots per trip
    for (; i + 1536 < hi; i += 2048) {
        unsigned int p0 = pairs[i], p1 = pairs[i + 512];
        unsigned int p2 = pairs[i + 1024], p3 = pairs[i + 1536];
        int s0 = p0 >> BSH, l0 = p0 & (BSZ - 1);
        int s1 = p1 >> BSH, l1 = p1 & (BSZ - 1);
        int s2 = p2 >> BSH, l2 = p2 & (BSZ - 1);
        int s3 = p3 >> BSH, l3 = p3 & (BSZ - 1);
        uint4 g0 = *(const uint4*)&HW[(size_t)s0 * 16 + h * 8];
        uint4 g1 = *(const uint4*)&HW[(size_t)s1 * 16 + h * 8];
        uint4 g2 = *(const uint4*)&HW[(size_t)s2 * 16 + h * 8];
        uint4 g3 = *(const uint4*)&HW[(size_t)s3 * 16 + h * 8];
        int* a0 = &iacc[l0 * 16 + h * 8];
        atomicAdd(&a0[0], __float2int_rn(b2f_lo(g0.x) * FPS));
        atomicAdd(&a0[1], __float2int_rn(b2f_hi(g0.x) * FPS));
        atomicAdd(&a0[2], __float2int_rn(b2f_lo(g0.y) * FPS));
        atomicAdd(&a0[3], __float2int_rn(b2f_hi(g0.y) * FPS));
        atomicAdd(&a0[4], __float2int_rn(b2f_lo(g0.z) * FPS));
        atomicAdd(&a0[5], __float2int_rn(b2f_hi(g0.z) * FPS));
        atomicAdd(&a0[6], __float2int_rn(b2f_lo(g0.w) * FPS));
        atomicAdd(&a0[7], __float2int_rn(b2f_hi(g0.w) * FPS));
        int* a1 = &iacc[l1 * 16 + h * 8];
        atomicAdd(&a1[0], __float2int_rn(b2f_lo(g1.x) * FPS));
        atomicAdd(&a1[1], __float2int_rn(b2f_hi(g1.x) * FPS));
        atomicAdd(&a1[2], __float2int_rn(b2f_lo(g1.y) * FPS));
        atomicAdd(&a1[3], __float2int_rn(b2f_hi(g1.y) * FPS));
        atomicAdd(&a1[4], __float2int_rn(b2f_lo(g1.z) * FPS));
        atomicAdd(&a1[5], __float2int_rn(b2f_hi(g1.z) * FPS));
        atomicAdd(&a1[6], __float2int_rn(b2f_lo(g1.w) * FPS));
        atomicAdd(&a1[7], __float2int_rn(b2f_hi(g1.w) * FPS));
        int* a2 = &iacc[l2 * 16 + h * 8];
        atomicAdd(&a2[0], __float2int_rn(b2f_lo(g2.x) * FPS));
        atomicAdd(&a2[1], __float2int_rn(b2f_hi(g2.x) * FPS));
        atomicAdd(&a2[2], __float2int_rn(b2f_lo(g2.y) * FPS));
        atomicAdd(&a2[3], __float2int_rn(b2f_hi(g2.y) * FPS));
        atomicAdd(&a2[4], __float2int_rn(b2f_lo(g2.z) * FPS));
        atomicAdd(&a2[5], __float2int_rn(b2f_hi(g2.z) * FPS));
        atomicAdd(&a2[6], __float2int_rn(b2f_lo(g2.w) * FPS));
        atomicAdd(&a2[7], __float2int_rn(b2f_hi(g2.w) * FPS));
        int* a3 = &iacc[l3 * 16 + h * 8];
        atomicAdd(&a3[0], __float2int_rn(b2f_lo(g3.x) * FPS));
        atomicAdd(&a3[1], __float2int_rn(b2f_hi(g3.x) * FPS));
        atomicAdd(&a3[2], __float2int_rn(b2f_lo(g3.y) * FPS));
        atomicAdd(&a3[3], __float2int_rn(b2f_hi(g3.y) * FPS));
        atomicAdd(&a3[4], __float2int_rn(b2f_lo(g3.z) * FPS));
        atomicAdd(&a3[5], __float2int_rn(b2f_hi(g3.z) * FPS));
        atomicAdd(&a3[6], __float2int_rn(b2f_lo(g3.w) * FPS));
        atomicAdd(&a3[7], __float2int_rn(b2f_hi(g3.w) * FPS));
        if (LAYER == 1 && h == 0) {
            atomicAdd(&rsl[l0], (unsigned int)(dinv[s0] * FPS + 0.5f));
            atomicAdd(&rsl[l1], (unsigned int)(dinv[s1] * FPS + 0.5f));
            atomicAdd(&rsl[l2], (unsigned int)(dinv[s2] * FPS + 0.5f));
            atomicAdd(&rsl[l3], (unsigned int)(dinv[s3] * FPS + 0.5f));
        }
    }
    for (; i < hi; i += 512) {
        unsigned int p0 = pairs[i];
        int s0 = p0 >> BSH, l0 = p0 & (BSZ - 1);
        uint4 g0 = *(const uint4*)&HW[(size_t)s0 * 16 + h * 8];
        int* a0 = &iacc[l0 * 16 + h * 8];
        atomicAdd(&a0[0], __float2int_rn(b2f_lo(g0.x) * FPS));
        atomicAdd(&a0[1], __float2int_rn(b2f_hi(g0.x) * FPS));
        atomicAdd(&a0[2], __float2int_rn(b2f_lo(g0.y) * FPS));
        atomicAdd(&a0[3], __float2int_rn(b2f_hi(g0.y) * FPS));
        atomicAdd(&a0[4], __float2int_rn(b2f_lo(g0.z) * FPS));
        atomicAdd(&a0[5], __float2int_rn(b2f_hi(g0.z) * FPS));
        atomicAdd(&a0[6], __float2int_rn(b2f_lo(g0.w) * FPS));
        atomicAdd(&a0[7], __float2int_rn(b2f_hi(g0.w) * FPS));
        if (LAYER == 1 && h == 0) atomicAdd(&rsl[l0], (unsigned int)(dinv[s0] * FPS + 0.5f));
    }
    __syncthreads();

    if (LAYER == 1) {
        int ln = t >> 1, f0 = (t & 1) * 8;
        int node = b * BSZ + ln;
        if (node < n) {
            float dd = dinv[node];
            const ushort4* sp = (const ushort4*)&HW[(size_t)node * 16 + f0];
            ushort4 s0 = sp[0], s1 = sp[1];
            const int* ap = &iacc[ln * 16 + f0];
            ushort4 o0, o1;
            o0.x = f2bf(dd * fmaxf(dd * ((float)ap[0] * FPI + b2f(s0.x)), 0.f));
            o0.y = f2bf(dd * fmaxf(dd * ((float)ap[1] * FPI + b2f(s0.y)), 0.f));
            o0.z = f2bf(dd * fmaxf(dd * ((float)ap[2] * FPI + b2f(s0.z)), 0.f));
            o0.w = f2bf(dd * fmaxf(dd * ((float)ap[3] * FPI + b2f(s0.w)), 0.f));
            o1.x = f2bf(dd * fmaxf(dd * ((float)ap[4] * FPI + b2f(s1.x)), 0.f));
            o1.y = f2bf(dd * fmaxf(dd * ((float)ap[5] * FPI + b2f(s1.y)), 0.f));
            o1.z = f2bf(dd * fmaxf(dd * ((float)ap[6] * FPI + b2f(s1.z)), 0.f));
            o1.w = f2bf(dd * fmaxf(dd * ((float)ap[7] * FPI + b2f(s1.w)), 0.f));
            ushort4* op = (ushort4*)&outA[(size_t)node * 16 + f0];
            op[0] = o0; op[1] = o1;
            if (f0 == 0) rowsum[node] = dd * (dd + (float)rsl[ln] * FPI);
        }
    } else {
        int wave = t >> 6, lane = t & 63;
        int node0 = b * BSZ;
        int nodeEnd = min(node0 + BSZ, n);
        for (int node = node0 + wave; node < nodeEnd; node += 16) {
            int ln = node - node0;
            float dd = dinv[node];
            float f[16];
            const ushort4* sp = (const ushort4*)&HW[(size_t)node * 16];
#pragma unroll
            for (int g = 0; g < 4; g++) {
                ushort4 u = sp[g];
                f[g * 4 + 0] = dd * ((float)iacc[ln * 16 + g * 4 + 0] * FPI + b2f(u.x));
                f[g * 4 + 1] = dd * ((float)iacc[ln * 16 + g * 4 + 1] * FPI + b2f(u.y));
                f[g * 4 + 2] = dd * ((float)iacc[ln * 16 + g * 4 + 2] * FPI + b2f(u.z));
                f[g * 4 + 3] = dd * ((float)iacc[ln * 16 + g * 4 + 3] * FPI + b2f(u.w));
            }
            float logit = -1e30f;
            if (lane < nc) {
                logit = rowsum[node] * B2[lane];
#pragma unroll
                for (int k = 0; k < 16; k++) logit = fmaf(f[k], W2[k * nc + lane], logit);
            }
            float m = logit;
#pragma unroll
            for (int off = 1; off < 64; off <<= 1) m = fmaxf(m, __shfl_xor(m, off, 64));
            float e = (lane < nc) ? __expf(logit - m) : 0.f;
            float s = e;
#pragma unroll
            for (int off = 1; off < 64; off <<= 1) s += __shfl_xor(s, off, 64);
            if (lane < nc) outF[(size_t)node * nc + lane] = logit - m - __logf(s);
        }
    }
}

// ---------------- launch ----------------

extern "C" void kernel_launch(void* const* d_in, const int* in_sizes, int n_in,
                              void* d_out, int out_size, void* d_ws, size_t ws_size,
                              hipStream_t stream) {
    const float* X  = (const float*)d_in[0];
    const int*   EI = (const int*)d_in[1];
    const float* W1 = (const float*)d_in[2];
    const float* B1 = (const float*)d_in[3];
    const float* W2 = (const float*)d_in[4];
    const float* B2 = (const float*)d_in[5];
    float* out = (float*)d_out;

    int NH = in_sizes[3];            // 16
    int NC = in_sizes[5];            // 40
    int NF = in_sizes[2] / NH;       // 512
    int n  = in_sizes[0] / NF;       // 100000
    int E  = in_sizes[1] / 2;        // 3200000
    const int* src = EI;
    const int* dst = EI + E;
    int nbk = (n + BSZ - 1) >> BSH;  // 196

    char* ws = (char*)d_ws;
    size_t o = 0;
    auto alloc = [&](size_t bytes) { size_t r = o; o = (o + bytes + 255) & ~(size_t)255; return r; };
    size_t o_dinv   = alloc((size_t)n * 4);
    size_t o_rsum   = alloc((size_t)n * 4);
    size_t o_curD   = alloc(1024);
    size_t o_curS   = alloc(1024);
    size_t o_pairs  = alloc((size_t)nbk * CAP * 4);
    size_t o_sbuf   = alloc((size_t)nbk * CAP * 2);
    size_t o_h1     = alloc((size_t)n * 16 * 4);
    size_t o_hw1    = alloc((size_t)n * 16 * 2);
    size_t o_a1w    = alloc((size_t)n * 16 * 2);

    float* dinv  = (float*)(ws + o_dinv);
    float* rsum  = (float*)(ws + o_rsum);
    int* curD    = (int*)(ws + o_curD);
    int* curS    = (int*)(ws + o_curS);
    unsigned int* pairs   = (unsigned int*)(ws + o_pairs);
    unsigned short* sbuf  = (unsigned short*)(ws + o_sbuf);
    float* h1    = (float*)(ws + o_h1);
    unsigned short* hw1 = (unsigned short*)(ws + o_hw1);
    unsigned short* a1w = (unsigned short*)(ws + o_a1w);

    init_k<<<1, 256, 0, stream>>>(curD, curS, nbk);

    int NBLK = (E + CHK - 1) / CHK;      // 782
    int nGm = (n + GROWS - 1) / GROWS;   // 1563
    fused_gs_k<<<nGm + NBLK, 256, 0, stream>>>(X, W1, B1, h1, n, nGm,
                                               src, dst, E, curD, curS,
                                               pairs, sbuf, nbk);
    dinvScale_k<<<nbk, 256, 0, stream>>>(sbuf, curS, h1, dinv, hw1, n);

    aggB_k<1><<<nbk, 1024, 0, stream>>>(pairs, curD, hw1, dinv, rsum,
                                        nullptr, nullptr, a1w, nullptr, n, NC);
    aggB_k<2><<<nbk, 1024, 0, stream>>>(pairs, curD, a1w, dinv, rsum,
                                        W2, B2, nullptr, out, n, NC);
}

// Round 24
// 202.965 us; speedup vs baseline: 1.0628x; 1.0628x over previous
//
#include <hip/hip_runtime.h>
#include <hip/hip_bf16.h>

#define BSH 9
#define BSZ 512    // nodes per bucket
#define CAP 17408  // edge capacity per bucket (mean 16384 + 8 sigma)
#define CHK 4096   // edges per scatter block (16 per thread)

typedef __attribute__((ext_vector_type(8))) short bf16x8;
typedef __attribute__((ext_vector_type(4))) float f32x4;

__device__ __forceinline__ unsigned short f2bf(float f) {  // RN-even fp32->bf16
    unsigned u = __float_as_uint(f);
    u += 0x7fffu + ((u >> 16) & 1u);
    return (unsigned short)(u >> 16);
}
__device__ __forceinline__ float b2f(unsigned short v) {
    return __uint_as_float((unsigned)v << 16);
}

// init bucket cursors to fixed bases
__global__ void init_k(int* __restrict__ curD, int* __restrict__ curS, int nbk) {
    int i = threadIdx.x;
    if (i < nbk) { curD[i] = i * CAP; curS[i] = i * CAP; }
}

// ---------------- fused: MFMA GEMM1 (coop W-frag staging) + bucket-sort scatter (R16) -------
// blocks [0, nGm): gemm (64 rows, 4 waves x one 16-row tile).
// blocks [nGm, nGm+NBLK): scatter.
// pairs packed: (src << 9) | (dst & 511).  sbuf: low 9 bits of src (ushort).

#define GROWS 64
#define GKC 256
#define GSTR 264   // bf16 row stride: 132 dwords == 4 mod 32 -> 2-way banks (free)

__global__ __launch_bounds__(256) void fused_gs_k(
    const float* __restrict__ X, const float* __restrict__ W, const float* __restrict__ B,
    float* __restrict__ H, int n, int nGm,
    const int* __restrict__ src, const int* __restrict__ dst, int E,
    int* __restrict__ curD, int* __restrict__ curS,
    unsigned int* __restrict__ pairs, unsigned short* __restrict__ sbuf, int nbk) {
    __shared__ char smem[GROWS * GSTR * 2];   // 33.8 KB union (gemm tile | scatter stage)
    int t = threadIdx.x;

    if ((int)blockIdx.x < nGm) {
        // ---- GEMM path ----
        unsigned short* xt = (unsigned short*)smem;
        int lane = t & 63, wave = t >> 6;
        int rowBase = blockIdx.x * GROWS;
        int bn = lane & 15;

        // cooperative W -> bf16 frag staging (frag table [16 kt][4 kg][16 bn][8 j] in xt)
        {
            int kt0 = t >> 4, kg0 = (t >> 2) & 3, bn0 = (t & 3) * 4;
            unsigned short frag[4][8];
#pragma unroll
            for (int j = 0; j < 8; ++j) {
                float4 w = *(const float4*)&W[(size_t)(kt0 * 32 + kg0 * 8 + j) * 16 + bn0];
                frag[0][j] = f2bf(w.x); frag[1][j] = f2bf(w.y);
                frag[2][j] = f2bf(w.z); frag[3][j] = f2bf(w.w);
            }
#pragma unroll
            for (int b = 0; b < 4; ++b)
                *(uint4*)&xt[((kt0 * 4 + kg0) * 16 + bn0 + b) * 8] = *(const uint4*)frag[b];
        }
        __syncthreads();
        bf16x8 bw[16];
#pragma unroll
        for (int kt = 0; kt < 16; ++kt)
            bw[kt] = *(const bf16x8*)&xt[(kt * 64 + lane) * 8];
        float bias = B[bn];
        __syncthreads();   // bw reads done before X staging overwrites

        f32x4 acc = {0.f, 0.f, 0.f, 0.f};
        int srow = t >> 4, skq = t & 15;

        for (int ch = 0; ch < 2; ++ch) {
#pragma unroll
            for (int p = 0; p < 4; ++p) {
                int r = p * 16 + srow;
                int gr = rowBase + r;
                const float* xr = &X[(size_t)(gr < n ? gr : n - 1) * 512 + ch * GKC + skq * 4];
#pragma unroll
                for (int q = 0; q < 4; ++q) {
                    float4 v = *(const float4*)&xr[q * 64];
                    ushort4 u;
                    u.x = f2bf(v.x); u.y = f2bf(v.y); u.z = f2bf(v.z); u.w = f2bf(v.w);
                    *(ushort4*)&xt[r * GSTR + skq * 4 + q * 64] = u;
                }
            }
            __syncthreads();

            int rb = (wave * 16 + bn) * GSTR + (lane >> 4) * 8;
#pragma unroll
            for (int kt = 0; kt < 8; ++kt) {
                bf16x8 af = *(const bf16x8*)&xt[rb + kt * 32];
                acc = __builtin_amdgcn_mfma_f32_16x16x32_bf16(af, bw[ch * 8 + kt], acc, 0, 0, 0);
            }
            __syncthreads();
        }

        int r0 = rowBase + wave * 16 + (lane >> 4) * 4;
#pragma unroll
        for (int i = 0; i < 4; ++i) {
            int row = r0 + i;
            if (row < n) H[(size_t)row * 16 + bn] = acc[i] + bias;
        }
    } else {
        // ---- scatter path: register-batched LDS bucket sort -> coalesced burst writes ----
        unsigned int*   stageD = (unsigned int*)smem;             // 4096 * 4B
        unsigned short* stageS = (unsigned short*)(smem + 16384); // 4096 * 2B
        int* cntD  = (int*)(smem + 24576);
        int* cntS  = (int*)(smem + 25600);
        int* rsvD  = (int*)(smem + 26624);
        int* rsvS  = (int*)(smem + 27648);
        int* scanD = (int*)(smem + 28672);
        int* scanS = (int*)(smem + 29696);
        int* ps    = (int*)(smem + 30720);

        int bb = blockIdx.x - nGm;
        int lo = bb * CHK, hi = min(E, lo + CHK);
        bool full = (hi - lo) == CHK;

        cntD[t] = 0; cntS[t] = 0;
        __syncthreads();

        int sv[16], dv[16];
        if (full) {
#pragma unroll
            for (int j = 0; j < 16; j++) {
                int i = lo + t + j * 256;
                sv[j] = src[i]; dv[j] = dst[i];
            }
#pragma unroll
            for (int j = 0; j < 16; j++) {
                atomicAdd(&cntD[dv[j] >> BSH], 1);
                atomicAdd(&cntS[sv[j] >> BSH], 1);
            }
        } else {
            for (int i = lo + t; i < hi; i += 256) {
                atomicAdd(&cntD[dst[i] >> BSH], 1);
                atomicAdd(&cntS[src[i] >> BSH], 1);
            }
        }
        __syncthreads();
        int vD = cntD[t];
        ps[t] = vD; __syncthreads();
        for (int o = 1; o < 256; o <<= 1) {
            int u = (t >= o) ? ps[t - o] : 0; __syncthreads();
            ps[t] += u; __syncthreads();
        }
        scanD[t] = ps[t] - vD;
        if (t < nbk && vD) rsvD[t] = atomicAdd(&curD[t], vD);
        __syncthreads();
        int vS = cntS[t];
        ps[t] = vS; __syncthreads();
        for (int o = 1; o < 256; o <<= 1) {
            int u = (t >= o) ? ps[t - o] : 0; __syncthreads();
            ps[t] += u; __syncthreads();
        }
        scanS[t] = ps[t] - vS;
        if (t < nbk && vS) rsvS[t] = atomicAdd(&curS[t], vS);
        cntD[t] = 0; cntS[t] = 0;
        __syncthreads();
        if (full) {
#pragma unroll
            for (int j = 0; j < 16; j++) {
                int s = sv[j], d = dv[j];
                int bd = d >> BSH;
                int pd = scanD[bd] + atomicAdd(&cntD[bd], 1);
                stageD[pd] = ((unsigned int)s << BSH) | (unsigned int)(d & (BSZ - 1));
                int bs = s >> BSH;
                int pp = scanS[bs] + atomicAdd(&cntS[bs], 1);
                stageS[pp] = (unsigned short)(s & (BSZ - 1));
            }
        } else {
            for (int i = lo + t; i < hi; i += 256) {
                int s = src[i], d = dst[i];
                int bd = d >> BSH;
                int pd = scanD[bd] + atomicAdd(&cntD[bd], 1);
                stageD[pd] = ((unsigned int)s << BSH) | (unsigned int)(d & (BSZ - 1));
                int bs = s >> BSH;
                int pp = scanS[bs] + atomicAdd(&cntS[bs], 1);
                stageS[pp] = (unsigned short)(s & (BSZ - 1));
            }
        }
        __syncthreads();
        int wave = t >> 6, lane = t & 63;
        for (int b = wave; b < nbk; b += 4) {
            int st = scanD[b], len = cntD[b], g = rsvD[b];
            for (int j = lane; j < len; j += 64) pairs[g + j] = stageD[st + j];
        }
        for (int b = wave; b < nbk; b += 4) {
            int st = scanS[b], len = cntS[b], g = rsvS[b];
            for (int j = lane; j < len; j += 64) sbuf[g + j] = stageS[st + j];
        }
    }
}

// ---------------- dinv (src-degree) + scale h1 -> bf16 hw1 (hw1 = dinv * h1) ----------------

__global__ __launch_bounds__(256) void dinvScale_k(const unsigned short* __restrict__ sbuf,
                                                   const int* __restrict__ curS,
                                                   const float* __restrict__ h1,
                                                   float* __restrict__ dinv,
                                                   unsigned short* __restrict__ hw1, int n) {
    __shared__ int cnt[BSZ];
    __shared__ float dl[BSZ];
    int b = blockIdx.x, t = threadIdx.x;
    cnt[t] = 0; cnt[t + 256] = 0;
    __syncthreads();
    int lo = b * CAP, hi = curS[b];
    for (int i = lo + t; i < hi; i += 256) atomicAdd(&cnt[sbuf[i]], 1);
    __syncthreads();
    int n0 = b * BSZ + t, n1 = n0 + 256;
    float d0 = rsqrtf((float)(1 + cnt[t]));
    float d1 = rsqrtf((float)(1 + cnt[t + 256]));
    dl[t] = d0; dl[t + 256] = d1;
    if (n0 < n) dinv[n0] = d0;
    if (n1 < n) dinv[n1] = d1;
    __syncthreads();
    int rows = min(BSZ, n - b * BSZ);
    int lim4 = rows * 4;
    size_t base = (size_t)b * BSZ * 16;
#pragma unroll
    for (int j = 0; j < 8; j++) {
        int i4 = j * 256 + t;
        if (i4 < lim4) {
            float4 v = *(const float4*)&h1[base + (size_t)i4 * 4];
            float d = dl[i4 >> 2];
            ushort4 u;
            u.x = f2bf(v.x * d); u.y = f2bf(v.y * d);
            u.z = f2bf(v.z * d); u.w = f2bf(v.w * d);
            *(ushort4*)&hw1[base + (size_t)i4 * 4] = u;
        }
    }
}

// ---------------- bucket-centric aggregation: PACKED u64 LDS atomics (8/edge + 1 cnt) -------
// value encoding: (v + 32) * 2^16 per 32-bit half, 2 features per u64 (halves stay positive,
// no cross-half carry; in-degree <= ~100 keeps halves < 2^31). Correction: -32*cnt at epilogue.

#define FPS 65536.f
#define FPI (1.f / 65536.f)
#define VBIAS 32.f

__device__ __forceinline__ unsigned long long pack2(float a, float b) {
    unsigned ea = __float2uint_rn((a + VBIAS) * FPS);
    unsigned eb = __float2uint_rn((b + VBIAS) * FPS);
    return ((unsigned long long)eb << 32) | ea;
}

template <int LAYER>
__global__ __launch_bounds__(1024) void aggB_k(
    const unsigned int* __restrict__ pairs, const int* __restrict__ curD,
    const unsigned short* __restrict__ HW, const float* __restrict__ dinv,
    float* __restrict__ rowsum, const float* __restrict__ W2,
    const float* __restrict__ B2, unsigned short* __restrict__ outA,
    float* __restrict__ outF, int n, int nc) {
    __shared__ unsigned long long iacc[BSZ * 8];  // 32 KB (8 u64 = 16 packed features)
    __shared__ unsigned int ecnt[BSZ];            // 2 KB edge counts (bias correction)
    __shared__ unsigned int rsl[BSZ];             // 2 KB (layer 1 rowsum)
    int b = blockIdx.x, t = threadIdx.x;
    for (int i = t; i < BSZ * 8; i += 1024) iacc[i] = 0ull;
    if (t < BSZ) ecnt[t] = 0u;
    if (LAYER == 1 && t >= BSZ && t < 2 * BSZ) rsl[t - BSZ] = 0u;
    __syncthreads();

    int lo = b * CAP, hi = curD[b];
    int q = t & 3;
    int i = lo + (t >> 2);
    for (; i + 768 < hi; i += 1024) {   // 4-deep: batch loads, gathers, then atomics
        unsigned int p0 = pairs[i], p1 = pairs[i + 256];
        unsigned int p2 = pairs[i + 512], p3 = pairs[i + 768];
        int s0 = p0 >> BSH, l0 = p0 & (BSZ - 1);
        int s1 = p1 >> BSH, l1 = p1 & (BSZ - 1);
        int s2 = p2 >> BSH, l2 = p2 & (BSZ - 1);
        int s3 = p3 >> BSH, l3 = p3 & (BSZ - 1);
        ushort4 u0 = *(const ushort4*)&HW[(size_t)s0 * 16 + q * 4];
        ushort4 u1 = *(const ushort4*)&HW[(size_t)s1 * 16 + q * 4];
        ushort4 u2 = *(const ushort4*)&HW[(size_t)s2 * 16 + q * 4];
        ushort4 u3 = *(const ushort4*)&HW[(size_t)s3 * 16 + q * 4];
        atomicAdd(&iacc[l0 * 8 + q * 2 + 0], pack2(b2f(u0.x), b2f(u0.y)));
        atomicAdd(&iacc[l0 * 8 + q * 2 + 1], pack2(b2f(u0.z), b2f(u0.w)));
        atomicAdd(&iacc[l1 * 8 + q * 2 + 0], pack2(b2f(u1.x), b2f(u1.y)));
        atomicAdd(&iacc[l1 * 8 + q * 2 + 1], pack2(b2f(u1.z), b2f(u1.w)));
        atomicAdd(&iacc[l2 * 8 + q * 2 + 0], pack2(b2f(u2.x), b2f(u2.y)));
        atomicAdd(&iacc[l2 * 8 + q * 2 + 1], pack2(b2f(u2.z), b2f(u2.w)));
        atomicAdd(&iacc[l3 * 8 + q * 2 + 0], pack2(b2f(u3.x), b2f(u3.y)));
        atomicAdd(&iacc[l3 * 8 + q * 2 + 1], pack2(b2f(u3.z), b2f(u3.w)));
        if (q == 0) {
            atomicAdd(&ecnt[l0], 1u); atomicAdd(&ecnt[l1], 1u);
            atomicAdd(&ecnt[l2], 1u); atomicAdd(&ecnt[l3], 1u);
        }
        if (LAYER == 1 && q == 1) {
            atomicAdd(&rsl[l0], (unsigned int)(dinv[s0] * FPS + 0.5f));
            atomicAdd(&rsl[l1], (unsigned int)(dinv[s1] * FPS + 0.5f));
            atomicAdd(&rsl[l2], (unsigned int)(dinv[s2] * FPS + 0.5f));
            atomicAdd(&rsl[l3], (unsigned int)(dinv[s3] * FPS + 0.5f));
        }
    }
    for (; i < hi; i += 256) {
        unsigned int p0 = pairs[i];
        int s0 = p0 >> BSH, l0 = p0 & (BSZ - 1);
        ushort4 u0 = *(const ushort4*)&HW[(size_t)s0 * 16 + q * 4];
        atomicAdd(&iacc[l0 * 8 + q * 2 + 0], pack2(b2f(u0.x), b2f(u0.y)));
        atomicAdd(&iacc[l0 * 8 + q * 2 + 1], pack2(b2f(u0.z), b2f(u0.w)));
        if (q == 0) atomicAdd(&ecnt[l0], 1u);
        if (LAYER == 1 && q == 1) atomicAdd(&rsl[l0], (unsigned int)(dinv[s0] * FPS + 0.5f));
    }
    __syncthreads();

    if (LAYER == 1) {
        int ln = t >> 1, f0 = (t & 1) * 8;
        int node = b * BSZ + ln;
        if (node < n) {
            float dd = dinv[node];
            float corr = VBIAS * (float)ecnt[ln];
            const ushort4* sp = (const ushort4*)&HW[(size_t)node * 16 + f0];
            ushort4 s0 = sp[0], s1 = sp[1];
            const unsigned long long* ap = &iacc[ln * 8 + (t & 1) * 4];
            float av[8];
#pragma unroll
            for (int g = 0; g < 4; g++) {
                unsigned long long pk = ap[g];
                av[g * 2 + 0] = (float)(unsigned)(pk & 0xffffffffull) * FPI - corr;
                av[g * 2 + 1] = (float)(unsigned)(pk >> 32) * FPI - corr;
            }
            ushort4 o0, o1;
            o0.x = f2bf(dd * fmaxf(dd * (av[0] + b2f(s0.x)), 0.f));
            o0.y = f2bf(dd * fmaxf(dd * (av[1] + b2f(s0.y)), 0.f));
            o0.z = f2bf(dd * fmaxf(dd * (av[2] + b2f(s0.z)), 0.f));
            o0.w = f2bf(dd * fmaxf(dd * (av[3] + b2f(s0.w)), 0.f));
            o1.x = f2bf(dd * fmaxf(dd * (av[4] + b2f(s1.x)), 0.f));
            o1.y = f2bf(dd * fmaxf(dd * (av[5] + b2f(s1.y)), 0.f));
            o1.z = f2bf(dd * fmaxf(dd * (av[6] + b2f(s1.z)), 0.f));
            o1.w = f2bf(dd * fmaxf(dd * (av[7] + b2f(s1.w)), 0.f));
            ushort4* op = (ushort4*)&outA[(size_t)node * 16 + f0];
            op[0] = o0; op[1] = o1;
            if (f0 == 0) rowsum[node] = dd * (dd + (float)rsl[ln] * FPI);
        }
    } else {
        int wave = t >> 6, lane = t & 63;
        int node0 = b * BSZ;
        int nodeEnd = min(node0 + BSZ, n);
        for (int node = node0 + wave; node < nodeEnd; node += 16) {
            int ln = node - node0;
            float dd = dinv[node];
            float corr = VBIAS * (float)ecnt[ln];
            float f[16];
            const ushort4* sp = (const ushort4*)&HW[(size_t)node * 16];
#pragma unroll
            for (int g = 0; g < 4; g++) {
                ushort4 u = sp[g];
                unsigned long long pkA = iacc[ln * 8 + g * 2 + 0];
                unsigned long long pkB = iacc[ln * 8 + g * 2 + 1];
                f[g * 4 + 0] = dd * ((float)(unsigned)(pkA & 0xffffffffull) * FPI - corr + b2f(u.x));
                f[g * 4 + 1] = dd * ((float)(unsigned)(pkA >> 32) * FPI - corr + b2f(u.y));
                f[g * 4 + 2] = dd * ((float)(unsigned)(pkB & 0xffffffffull) * FPI - corr + b2f(u.z));
                f[g * 4 + 3] = dd * ((float)(unsigned)(pkB >> 32) * FPI - corr + b2f(u.w));
            }
            float logit = -1e30f;
            if (lane < nc) {
                logit = rowsum[node] * B2[lane];
#pragma unroll
                for (int k = 0; k < 16; k++) logit = fmaf(f[k], W2[k * nc + lane], logit);
            }
            float m = logit;
#pragma unroll
            for (int off = 1; off < 64; off <<= 1) m = fmaxf(m, __shfl_xor(m, off, 64));
            float e = (lane < nc) ? __expf(logit - m) : 0.f;
            float s = e;
#pragma unroll
            for (int off = 1; off < 64; off <<= 1) s += __shfl_xor(s, off, 64);
            if (lane < nc) outF[(size_t)node * nc + lane] = logit - m - __logf(s);
        }
    }
}

// ---------------- launch ----------------

extern "C" void kernel_launch(void* const* d_in, const int* in_sizes, int n_in,
                              void* d_out, int out_size, void* d_ws, size_t ws_size,
                              hipStream_t stream) {
    const float* X  = (const float*)d_in[0];
    const int*   EI = (const int*)d_in[1];
    const float* W1 = (const float*)d_in[2];
    const float* B1 = (const float*)d_in[3];
    const float* W2 = (const float*)d_in[4];
    const float* B2 = (const float*)d_in[5];
    float* out = (float*)d_out;

    int NH = in_sizes[3];            // 16
    int NC = in_sizes[5];            // 40
    int NF = in_sizes[2] / NH;       // 512
    int n  = in_sizes[0] / NF;       // 100000
    int E  = in_sizes[1] / 2;        // 3200000
    const int* src = EI;
    const int* dst = EI + E;
    int nbk = (n + BSZ - 1) >> BSH;  // 196

    char* ws = (char*)d_ws;
    size_t o = 0;
    auto alloc = [&](size_t bytes) { size_t r = o; o = (o + bytes + 255) & ~(size_t)255; return r; };
    size_t o_dinv   = alloc((size_t)n * 4);
    size_t o_rsum   = alloc((size_t)n * 4);
    size_t o_curD   = alloc(1024);
    size_t o_curS   = alloc(1024);
    size_t o_pairs  = alloc((size_t)nbk * CAP * 4);
    size_t o_sbuf   = alloc((size_t)nbk * CAP * 2);
    size_t o_h1     = alloc((size_t)n * 16 * 4);
    size_t o_hw1    = alloc((size_t)n * 16 * 2);
    size_t o_a1w    = alloc((size_t)n * 16 * 2);

    float* dinv  = (float*)(ws + o_dinv);
    float* rsum  = (float*)(ws + o_rsum);
    int* curD    = (int*)(ws + o_curD);
    int* curS    = (int*)(ws + o_curS);
    unsigned int* pairs   = (unsigned int*)(ws + o_pairs);
    unsigned short* sbuf  = (unsigned short*)(ws + o_sbuf);
    float* h1    = (float*)(ws + o_h1);
    unsigned short* hw1 = (unsigned short*)(ws + o_hw1);
    unsigned short* a1w = (unsigned short*)(ws + o_a1w);

    init_k<<<1, 256, 0, stream>>>(curD, curS, nbk);

    int NBLK = (E + CHK - 1) / CHK;      // 782
    int nGm = (n + GROWS - 1) / GROWS;   // 1563
    fused_gs_k<<<nGm + NBLK, 256, 0, stream>>>(X, W1, B1, h1, n, nGm,
                                               src, dst, E, curD, curS,
                                               pairs, sbuf, nbk);
    dinvScale_k<<<nbk, 256, 0, stream>>>(sbuf, curS, h1, dinv, hw1, n);

    aggB_k<1><<<nbk, 1024, 0, stream>>>(pairs, curD, hw1, dinv, rsum,
                                        nullptr, nullptr, a1w, nullptr, n, NC);
    aggB_k<2><<<nbk, 1024, 0, stream>>>(pairs, curD, a1w, dinv, rsum,
                                        W2, B2, nullptr, out, n, NC);
}

// Round 25
// 197.837 us; speedup vs baseline: 1.0903x; 1.0259x over previous
//
#include <hip/hip_runtime.h>
#include <hip/hip_bf16.h>

#define BSH 9
#define BSZ 512    // nodes per bucket
#define CAP 17408  // edge capacity per bucket (mean 16384 + 8 sigma)
#define CHK 4096   // edges per scatter block (16 per thread)

typedef __attribute__((ext_vector_type(8))) short bf16x8;
typedef __attribute__((ext_vector_type(4))) float f32x4;

__device__ __forceinline__ unsigned short f2bf(float f) {  // RN-even fp32->bf16
    unsigned u = __float_as_uint(f);
    u += 0x7fffu + ((u >> 16) & 1u);
    return (unsigned short)(u >> 16);
}
__device__ __forceinline__ float b2f(unsigned short v) {
    return __uint_as_float((unsigned)v << 16);
}

// init bucket cursors to fixed bases
__global__ void init_k(int* __restrict__ curD, int* __restrict__ curS, int nbk) {
    int i = threadIdx.x;
    if (i < nbk) { curD[i] = i * CAP; curS[i] = i * CAP; }
}

// ---------------- fused: MFMA GEMM1 (coop W-frag staging) + bucket-sort scatter -------------
// blocks [0, nGm): gemm (64 rows, 4 waves x one 16-row tile).
// blocks [nGm, nGm+NBLK): scatter.
// pairs packed: (src << 9) | (dst & 511).  sbuf: low 9 bits of src (ushort).

#define GROWS 64
#define GKC 256
#define GSTR 264   // bf16 row stride: 132 dwords == 4 mod 32 -> 2-way banks (free)

__global__ __launch_bounds__(256) void fused_gs_k(
    const float* __restrict__ X, const float* __restrict__ W, const float* __restrict__ B,
    float* __restrict__ H, int n, int nGm,
    const int* __restrict__ src, const int* __restrict__ dst, int E,
    int* __restrict__ curD, int* __restrict__ curS,
    unsigned int* __restrict__ pairs, unsigned short* __restrict__ sbuf, int nbk) {
    __shared__ char smem[GROWS * GSTR * 2];   // 33.8 KB union (gemm tile | scatter stage)
    int t = threadIdx.x;

    if ((int)blockIdx.x < nGm) {
        // ---- GEMM path ----
        unsigned short* xt = (unsigned short*)smem;
        int lane = t & 63, wave = t >> 6;
        int rowBase = blockIdx.x * GROWS;
        int bn = lane & 15;

        // cooperative W -> bf16 frag staging (frag table [16 kt][4 kg][16 bn][8 j] in xt)
        {
            int kt0 = t >> 4, kg0 = (t >> 2) & 3, bn0 = (t & 3) * 4;
            unsigned short frag[4][8];
#pragma unroll
            for (int j = 0; j < 8; ++j) {
                float4 w = *(const float4*)&W[(size_t)(kt0 * 32 + kg0 * 8 + j) * 16 + bn0];
                frag[0][j] = f2bf(w.x); frag[1][j] = f2bf(w.y);
                frag[2][j] = f2bf(w.z); frag[3][j] = f2bf(w.w);
            }
#pragma unroll
            for (int b = 0; b < 4; ++b)
                *(uint4*)&xt[((kt0 * 4 + kg0) * 16 + bn0 + b) * 8] = *(const uint4*)frag[b];
        }
        __syncthreads();
        bf16x8 bw[16];
#pragma unroll
        for (int kt = 0; kt < 16; ++kt)
            bw[kt] = *(const bf16x8*)&xt[(kt * 64 + lane) * 8];
        float bias = B[bn];
        __syncthreads();   // bw reads done before X staging overwrites

        f32x4 acc = {0.f, 0.f, 0.f, 0.f};
        int srow = t >> 4, skq = t & 15;

        for (int ch = 0; ch < 2; ++ch) {
#pragma unroll
            for (int p = 0; p < 4; ++p) {
                int r = p * 16 + srow;
                int gr = rowBase + r;
                const float* xr = &X[(size_t)(gr < n ? gr : n - 1) * 512 + ch * GKC + skq * 4];
#pragma unroll
                for (int q = 0; q < 4; ++q) {
                    float4 v = *(const float4*)&xr[q * 64];
                    ushort4 u;
                    u.x = f2bf(v.x); u.y = f2bf(v.y); u.z = f2bf(v.z); u.w = f2bf(v.w);
                    *(ushort4*)&xt[r * GSTR + skq * 4 + q * 64] = u;
                }
            }
            __syncthreads();

            int rb = (wave * 16 + bn) * GSTR + (lane >> 4) * 8;
#pragma unroll
            for (int kt = 0; kt < 8; ++kt) {
                bf16x8 af = *(const bf16x8*)&xt[rb + kt * 32];
                acc = __builtin_amdgcn_mfma_f32_16x16x32_bf16(af, bw[ch * 8 + kt], acc, 0, 0, 0);
            }
            __syncthreads();
        }

        int r0 = rowBase + wave * 16 + (lane >> 4) * 4;
#pragma unroll
        for (int i = 0; i < 4; ++i) {
            int row = r0 + i;
            if (row < n) H[(size_t)row * 16 + bn] = acc[i] + bias;
        }
    } else {
        // ---- scatter path: register-batched LDS bucket sort -> coalesced burst writes ----
        unsigned int*   stageD = (unsigned int*)smem;             // 4096 * 4B
        unsigned short* stageS = (unsigned short*)(smem + 16384); // 4096 * 2B
        int* cntD  = (int*)(smem + 24576);
        int* cntS  = (int*)(smem + 25600);
        int* rsvD  = (int*)(smem + 26624);
        int* rsvS  = (int*)(smem + 27648);
        int* scanD = (int*)(smem + 28672);
        int* scanS = (int*)(smem + 29696);
        int* ps    = (int*)(smem + 30720);

        int bb = blockIdx.x - nGm;
        int lo = bb * CHK, hi = min(E, lo + CHK);
        bool full = (hi - lo) == CHK;

        cntD[t] = 0; cntS[t] = 0;
        __syncthreads();

        int sv[16], dv[16];
        if (full) {
#pragma unroll
            for (int j = 0; j < 16; j++) {
                int i = lo + t + j * 256;
                sv[j] = src[i]; dv[j] = dst[i];
            }
#pragma unroll
            for (int j = 0; j < 16; j++) {
                atomicAdd(&cntD[dv[j] >> BSH], 1);
                atomicAdd(&cntS[sv[j] >> BSH], 1);
            }
        } else {
            for (int i = lo + t; i < hi; i += 256) {
                atomicAdd(&cntD[dst[i] >> BSH], 1);
                atomicAdd(&cntS[src[i] >> BSH], 1);
            }
        }
        __syncthreads();
        int vD = cntD[t];
        ps[t] = vD; __syncthreads();
        for (int o = 1; o < 256; o <<= 1) {
            int u = (t >= o) ? ps[t - o] : 0; __syncthreads();
            ps[t] += u; __syncthreads();
        }
        scanD[t] = ps[t] - vD;
        if (t < nbk && vD) rsvD[t] = atomicAdd(&curD[t], vD);
        __syncthreads();
        int vS = cntS[t];
        ps[t] = vS; __syncthreads();
        for (int o = 1; o < 256; o <<= 1) {
            int u = (t >= o) ? ps[t - o] : 0; __syncthreads();
            ps[t] += u; __syncthreads();
        }
        scanS[t] = ps[t] - vS;
        if (t < nbk && vS) rsvS[t] = atomicAdd(&curS[t], vS);
        cntD[t] = 0; cntS[t] = 0;
        __syncthreads();
        if (full) {
#pragma unroll
            for (int j = 0; j < 16; j++) {
                int s = sv[j], d = dv[j];
                int bd = d >> BSH;
                int pd = scanD[bd] + atomicAdd(&cntD[bd], 1);
                stageD[pd] = ((unsigned int)s << BSH) | (unsigned int)(d & (BSZ - 1));
                int bs = s >> BSH;
                int pp = scanS[bs] + atomicAdd(&cntS[bs], 1);
                stageS[pp] = (unsigned short)(s & (BSZ - 1));
            }
        } else {
            for (int i = lo + t; i < hi; i += 256) {
                int s = src[i], d = dst[i];
                int bd = d >> BSH;
                int pd = scanD[bd] + atomicAdd(&cntD[bd], 1);
                stageD[pd] = ((unsigned int)s << BSH) | (unsigned int)(d & (BSZ - 1));
                int bs = s >> BSH;
                int pp = scanS[bs] + atomicAdd(&cntS[bs], 1);
                stageS[pp] = (unsigned short)(s & (BSZ - 1));
            }
        }
        __syncthreads();
        int wave = t >> 6, lane = t & 63;
        for (int b = wave; b < nbk; b += 4) {
            int st = scanD[b], len = cntD[b], g = rsvD[b];
            for (int j = lane; j < len; j += 64) pairs[g + j] = stageD[st + j];
        }
        for (int b = wave; b < nbk; b += 4) {
            int st = scanS[b], len = cntS[b], g = rsvS[b];
            for (int j = lane; j < len; j += 64) sbuf[g + j] = stageS[st + j];
        }
    }
}

// ---------------- dinv (src-degree) + scale h1 -> bf16 hw1 (hw1 = dinv * h1) ----------------

__global__ __launch_bounds__(256) void dinvScale_k(const unsigned short* __restrict__ sbuf,
                                                   const int* __restrict__ curS,
                                                   const float* __restrict__ h1,
                                                   float* __restrict__ dinv,
                                                   unsigned short* __restrict__ hw1, int n) {
    __shared__ int cnt[BSZ];
    __shared__ float dl[BSZ];
    int b = blockIdx.x, t = threadIdx.x;
    cnt[t] = 0; cnt[t + 256] = 0;
    __syncthreads();
    int lo = b * CAP, hi = curS[b];
    for (int i = lo + t; i < hi; i += 256) atomicAdd(&cnt[sbuf[i]], 1);
    __syncthreads();
    int n0 = b * BSZ + t, n1 = n0 + 256;
    float d0 = rsqrtf((float)(1 + cnt[t]));
    float d1 = rsqrtf((float)(1 + cnt[t + 256]));
    dl[t] = d0; dl[t + 256] = d1;
    if (n0 < n) dinv[n0] = d0;
    if (n1 < n) dinv[n1] = d1;
    __syncthreads();
    int rows = min(BSZ, n - b * BSZ);
    int lim4 = rows * 4;
    size_t base = (size_t)b * BSZ * 16;
#pragma unroll
    for (int j = 0; j < 8; j++) {
        int i4 = j * 256 + t;
        if (i4 < lim4) {
            float4 v = *(const float4*)&h1[base + (size_t)i4 * 4];
            float d = dl[i4 >> 2];
            ushort4 u;
            u.x = f2bf(v.x * d); u.y = f2bf(v.y * d);
            u.z = f2bf(v.z * d); u.w = f2bf(v.w * d);
            *(ushort4*)&hw1[base + (size_t)i4 * 4] = u;
        }
    }
}

// ---------------- bucket-centric aggregation (INT fixed-point LDS atomics, 4-deep ILP) ------
// One block per dst-bucket; iacc[512][16] int (val*2^16) in LDS; edges streamed from pairs.
// LAYER 1: epilogue = self + relu + premult + bf16 store + rowsum.
// LAYER 2: epilogue = self + logits + log_softmax.

#define FPS 65536.f
#define FPI (1.f / 65536.f)

template <int LAYER>
__global__ __launch_bounds__(1024) void aggB_k(
    const unsigned int* __restrict__ pairs, const int* __restrict__ curD,
    const unsigned short* __restrict__ HW, const float* __restrict__ dinv,
    float* __restrict__ rowsum, const float* __restrict__ W2,
    const float* __restrict__ B2, unsigned short* __restrict__ outA,
    float* __restrict__ outF, int n, int nc) {
    __shared__ int iacc[BSZ * 16];        // 32 KB
    __shared__ unsigned int rsl[BSZ];     // 2 KB (layer 1)
    int b = blockIdx.x, t = threadIdx.x;
    for (int i = t; i < BSZ * 16; i += 1024) iacc[i] = 0;
    if (LAYER == 1 && t < BSZ) rsl[t] = 0u;
    __syncthreads();

    int lo = b * CAP, hi = curD[b];
    int q = t & 3;
    int i = lo + (t >> 2);
    for (; i + 768 < hi; i += 1024) {
        unsigned int p0 = pairs[i], p1 = pairs[i + 256];
        unsigned int p2 = pairs[i + 512], p3 = pairs[i + 768];
        int s0 = p0 >> BSH, l0 = p0 & (BSZ - 1);
        int s1 = p1 >> BSH, l1 = p1 & (BSZ - 1);
        int s2 = p2 >> BSH, l2 = p2 & (BSZ - 1);
        int s3 = p3 >> BSH, l3 = p3 & (BSZ - 1);
        ushort4 u0 = *(const ushort4*)&HW[(size_t)s0 * 16 + q * 4];
        ushort4 u1 = *(const ushort4*)&HW[(size_t)s1 * 16 + q * 4];
        ushort4 u2 = *(const ushort4*)&HW[(size_t)s2 * 16 + q * 4];
        ushort4 u3 = *(const ushort4*)&HW[(size_t)s3 * 16 + q * 4];
        int* a0 = &iacc[l0 * 16 + q * 4];
        atomicAdd(&a0[0], __float2int_rn(b2f(u0.x) * FPS));
        atomicAdd(&a0[1], __float2int_rn(b2f(u0.y) * FPS));
        atomicAdd(&a0[2], __float2int_rn(b2f(u0.z) * FPS));
        atomicAdd(&a0[3], __float2int_rn(b2f(u0.w) * FPS));
        int* a1 = &iacc[l1 * 16 + q * 4];
        atomicAdd(&a1[0], __float2int_rn(b2f(u1.x) * FPS));
        atomicAdd(&a1[1], __float2int_rn(b2f(u1.y) * FPS));
        atomicAdd(&a1[2], __float2int_rn(b2f(u1.z) * FPS));
        atomicAdd(&a1[3], __float2int_rn(b2f(u1.w) * FPS));
        int* a2 = &iacc[l2 * 16 + q * 4];
        atomicAdd(&a2[0], __float2int_rn(b2f(u2.x) * FPS));
        atomicAdd(&a2[1], __float2int_rn(b2f(u2.y) * FPS));
        atomicAdd(&a2[2], __float2int_rn(b2f(u2.z) * FPS));
        atomicAdd(&a2[3], __float2int_rn(b2f(u2.w) * FPS));
        int* a3 = &iacc[l3 * 16 + q * 4];
        atomicAdd(&a3[0], __float2int_rn(b2f(u3.x) * FPS));
        atomicAdd(&a3[1], __float2int_rn(b2f(u3.y) * FPS));
        atomicAdd(&a3[2], __float2int_rn(b2f(u3.z) * FPS));
        atomicAdd(&a3[3], __float2int_rn(b2f(u3.w) * FPS));
        if (LAYER == 1 && q == 0) {
            atomicAdd(&rsl[l0], (unsigned int)(dinv[s0] * FPS + 0.5f));
            atomicAdd(&rsl[l1], (unsigned int)(dinv[s1] * FPS + 0.5f));
            atomicAdd(&rsl[l2], (unsigned int)(dinv[s2] * FPS + 0.5f));
            atomicAdd(&rsl[l3], (unsigned int)(dinv[s3] * FPS + 0.5f));
        }
    }
    for (; i < hi; i += 256) {
        unsigned int p0 = pairs[i];
        int s0 = p0 >> BSH, l0 = p0 & (BSZ - 1);
        ushort4 u0 = *(const ushort4*)&HW[(size_t)s0 * 16 + q * 4];
        int* a0 = &iacc[l0 * 16 + q * 4];
        atomicAdd(&a0[0], __float2int_rn(b2f(u0.x) * FPS));
        atomicAdd(&a0[1], __float2int_rn(b2f(u0.y) * FPS));
        atomicAdd(&a0[2], __float2int_rn(b2f(u0.z) * FPS));
        atomicAdd(&a0[3], __float2int_rn(b2f(u0.w) * FPS));
        if (LAYER == 1 && q == 0) atomicAdd(&rsl[l0], (unsigned int)(dinv[s0] * FPS + 0.5f));
    }
    __syncthreads();

    if (LAYER == 1) {
        int ln = t >> 1, f0 = (t & 1) * 8;
        int node = b * BSZ + ln;
        if (node < n) {
            float dd = dinv[node];
            const ushort4* sp = (const ushort4*)&HW[(size_t)node * 16 + f0];
            ushort4 s0 = sp[0], s1 = sp[1];
            const int* ap = &iacc[ln * 16 + f0];
            ushort4 o0, o1;
            o0.x = f2bf(dd * fmaxf(dd * ((float)ap[0] * FPI + b2f(s0.x)), 0.f));
            o0.y = f2bf(dd * fmaxf(dd * ((float)ap[1] * FPI + b2f(s0.y)), 0.f));
            o0.z = f2bf(dd * fmaxf(dd * ((float)ap[2] * FPI + b2f(s0.z)), 0.f));
            o0.w = f2bf(dd * fmaxf(dd * ((float)ap[3] * FPI + b2f(s0.w)), 0.f));
            o1.x = f2bf(dd * fmaxf(dd * ((float)ap[4] * FPI + b2f(s1.x)), 0.f));
            o1.y = f2bf(dd * fmaxf(dd * ((float)ap[5] * FPI + b2f(s1.y)), 0.f));
            o1.z = f2bf(dd * fmaxf(dd * ((float)ap[6] * FPI + b2f(s1.z)), 0.f));
            o1.w = f2bf(dd * fmaxf(dd * ((float)ap[7] * FPI + b2f(s1.w)), 0.f));
            ushort4* op = (ushort4*)&outA[(size_t)node * 16 + f0];
            op[0] = o0; op[1] = o1;
            if (f0 == 0) rowsum[node] = dd * (dd + (float)rsl[ln] * FPI);
        }
    } else {
        int wave = t >> 6, lane = t & 63;
        int node0 = b * BSZ;
        int nodeEnd = min(node0 + BSZ, n);
        for (int node = node0 + wave; node < nodeEnd; node += 16) {
            int ln = node - node0;
            float dd = dinv[node];
            float f[16];
            const ushort4* sp = (const ushort4*)&HW[(size_t)node * 16];
#pragma unroll
            for (int g = 0; g < 4; g++) {
                ushort4 u = sp[g];
                f[g * 4 + 0] = dd * ((float)iacc[ln * 16 + g * 4 + 0] * FPI + b2f(u.x));
                f[g * 4 + 1] = dd * ((float)iacc[ln * 16 + g * 4 + 1] * FPI + b2f(u.y));
                f[g * 4 + 2] = dd * ((float)iacc[ln * 16 + g * 4 + 2] * FPI + b2f(u.z));
                f[g * 4 + 3] = dd * ((float)iacc[ln * 16 + g * 4 + 3] * FPI + b2f(u.w));
            }
            float logit = -1e30f;
            if (lane < nc) {
                logit = rowsum[node] * B2[lane];
#pragma unroll
                for (int k = 0; k < 16; k++) logit = fmaf(f[k], W2[k * nc + lane], logit);
            }
            float m = logit;
#pragma unroll
            for (int off = 1; off < 64; off <<= 1) m = fmaxf(m, __shfl_xor(m, off, 64));
            float e = (lane < nc) ? __expf(logit - m) : 0.f;
            float s = e;
#pragma unroll
            for (int off = 1; off < 64; off <<= 1) s += __shfl_xor(s, off, 64);
            if (lane < nc) outF[(size_t)node * nc + lane] = logit - m - __logf(s);
        }
    }
}

// ---------------- launch ----------------

extern "C" void kernel_launch(void* const* d_in, const int* in_sizes, int n_in,
                              void* d_out, int out_size, void* d_ws, size_t ws_size,
                              hipStream_t stream) {
    const float* X  = (const float*)d_in[0];
    const int*   EI = (const int*)d_in[1];
    const float* W1 = (const float*)d_in[2];
    const float* B1 = (const float*)d_in[3];
    const float* W2 = (const float*)d_in[4];
    const float* B2 = (const float*)d_in[5];
    float* out = (float*)d_out;

    int NH = in_sizes[3];            // 16
    int NC = in_sizes[5];            // 40
    int NF = in_sizes[2] / NH;       // 512
    int n  = in_sizes[0] / NF;       // 100000
    int E  = in_sizes[1] / 2;        // 3200000
    const int* src = EI;
    const int* dst = EI + E;
    int nbk = (n + BSZ - 1) >> BSH;  // 196

    char* ws = (char*)d_ws;
    size_t o = 0;
    auto alloc = [&](size_t bytes) { size_t r = o; o = (o + bytes + 255) & ~(size_t)255; return r; };
    size_t o_dinv   = alloc((size_t)n * 4);
    size_t o_rsum   = alloc((size_t)n * 4);
    size_t o_curD   = alloc(1024);
    size_t o_curS   = alloc(1024);
    size_t o_pairs  = alloc((size_t)nbk * CAP * 4);
    size_t o_sbuf   = alloc((size_t)nbk * CAP * 2);
    size_t o_h1     = alloc((size_t)n * 16 * 4);
    size_t o_hw1    = alloc((size_t)n * 16 * 2);
    size_t o_a1w    = alloc((size_t)n * 16 * 2);

    float* dinv  = (float*)(ws + o_dinv);
    float* rsum  = (float*)(ws + o_rsum);
    int* curD    = (int*)(ws + o_curD);
    int* curS    = (int*)(ws + o_curS);
    unsigned int* pairs   = (unsigned int*)(ws + o_pairs);
    unsigned short* sbuf  = (unsigned short*)(ws + o_sbuf);
    float* h1    = (float*)(ws + o_h1);
    unsigned short* hw1 = (unsigned short*)(ws + o_hw1);
    unsigned short* a1w = (unsigned short*)(ws + o_a1w);

    init_k<<<1, 256, 0, stream>>>(curD, curS, nbk);

    int NBLK = (E + CHK - 1) / CHK;      // 782
    int nGm = (n + GROWS - 1) / GROWS;   // 1563
    fused_gs_k<<<nGm + NBLK, 256, 0, stream>>>(X, W1, B1, h1, n, nGm,
                                               src, dst, E, curD, curS,
                                               pairs, sbuf, nbk);
    dinvScale_k<<<nbk, 256, 0, stream>>>(sbuf, curS, h1, dinv, hw1, n);

    aggB_k<1><<<nbk, 1024, 0, stream>>>(pairs, curD, hw1, dinv, rsum,
                                        nullptr, nullptr, a1w, nullptr, n, NC);
    aggB_k<2><<<nbk, 1024, 0, stream>>>(pairs, curD, a1w, dinv, rsum,
                                        W2, B2, nullptr, out, n, NC);
}